// Round 18
// baseline (124.564 us; speedup 1.0000x reference)
//
#include <hip/hip_runtime.h>

// TsSub: out[b, p, t] = x[b, I[p], t*10] - x[b, J[p], t*10]
// x: (256, 64, 2000) f32, out: (256, 2016, 200) f32, (I,J)=triu_indices(64,k=1)
//
// R18: one block/batch, 4-phase PAIR-CHUNK pipeline.
// Rows chunked 4x16. After rows < 16(c+1) staged, all pairs with
// max(i,j) in chunk c are emittable as FULL 800B rows (store lesson R7/14/15:
// never split a row). Phase: issue chunk c+1 loads -> sched_barrier ->
// emit chunk c (stores overlap in-flight reads) -> extract regs->LDS ->
// barrier. Only chunk0's read (33MB GPU-wide) is exposed.
// Emit order within chunk = memory order (16-row runs for i<16c, then
// triangle) so stores stay sequential.

#define NF     64
#define T_OUT  200
#define NPAIR  2016
#define NB     256
#define RF4    500     // vec4 per x row
#define TV4    50      // vec4 per out row
#define NT     1024
#define CH     3200    // samples per 16-row chunk

typedef float fx4 __attribute__((ext_vector_type(4)));

__global__ __launch_bounds__(NT)
void ts_sub_pipe(const fx4* __restrict__ xv, fx4* __restrict__ out) {
    __shared__ __attribute__((aligned(16))) float sf[NF * T_OUT];  // 51.2 KB
    __shared__ unsigned char  ir[NPAIR];
    __shared__ unsigned char  jr[NPAIR];
    __shared__ unsigned short obr[NPAIR];

    const int tid = threadIdx.x;
    const int b   = blockIdx.x;
    const fx4* __restrict__ xb = xv + (size_t)b * (NF * RF4);
    fx4* __restrict__ ob = out + (size_t)b * (NPAIR * TV4);
    const fx4* __restrict__ s4 = reinterpret_cast<const fx4*>(sf); // stride 50

// issue 16-row chunk C into 4 named vec4 regs (sample k: vec4 5*(k>>1)+2*(k&1))
#define ISSUE(C, R0, R1, R2, R3)                                              \
    {                                                                         \
        int l = tid;                                                          \
        { int r = l / 200, k = l - 200 * r;                                   \
          R0 = __builtin_nontemporal_load(                                    \
                   &xb[(16*(C)+r)*RF4 + 5*(k>>1) + 2*(k&1)]); }               \
        l += NT;                                                              \
        { int r = l / 200, k = l - 200 * r;                                   \
          R1 = __builtin_nontemporal_load(                                    \
                   &xb[(16*(C)+r)*RF4 + 5*(k>>1) + 2*(k&1)]); }               \
        l += NT;                                                              \
        { int r = l / 200, k = l - 200 * r;                                   \
          R2 = __builtin_nontemporal_load(                                    \
                   &xb[(16*(C)+r)*RF4 + 5*(k>>1) + 2*(k&1)]); }               \
        l += NT;                                                              \
        if (l < CH) { int r = l / 200, k = l - 200 * r;                       \
          R3 = __builtin_nontemporal_load(                                    \
                   &xb[(16*(C)+r)*RF4 + 5*(k>>1) + 2*(k&1)]); }               \
    }

// extract chunk C regs -> sf[C*CH + l]  (k parity == l parity, 200 even)
#define EXTRACT(C, R0, R1, R2, R3)                                            \
    {                                                                         \
        int l = tid;                                                          \
        sf[(C)*CH + l] = (l & 1) ? R0.z : R0.x;  l += NT;                     \
        sf[(C)*CH + l] = (l & 1) ? R1.z : R1.x;  l += NT;                     \
        sf[(C)*CH + l] = (l & 1) ? R2.z : R2.x;  l += NT;                     \
        if (l < CH) sf[(C)*CH + l] = (l & 1) ? R3.z : R3.x;                   \
    }

// emit chunk's pairs: table entries [OFFC, OFFC+NC), 50 vec4 each, nt stores
#define EMIT(OFFC, NC)                                                        \
    {                                                                         \
        int p  = tid / TV4;                                                   \
        int t4 = tid - p * TV4;                                               \
        for (int v = tid; v < (NC) * TV4; v += NT) {                          \
            int g = (OFFC) + p;                                               \
            fx4 A  = s4[ir[g] * TV4 + t4];                                    \
            fx4 Cc = s4[jr[g] * TV4 + t4];                                    \
            __builtin_nontemporal_store(A - Cc,                               \
                &ob[(size_t)obr[g] * TV4 + t4]);                              \
            p += 20; t4 += 24;                    /* 1024 = 20*50 + 24 */     \
            if (t4 >= TV4) { t4 -= TV4; ++p; }                                \
        }                                                                     \
    }

    fx4 a0{}, a1{}, a2{}, a3{}, b0{}, b1{}, b2{}, b3{};
    fx4 c0{}, c1{}, c2{}, c3{}, d0{}, d1{}, d2{}, d3{};

    ISSUE(0, a0, a1, a2, a3)

    // --- pair tables, chunk-grouped, memory-ordered within chunk ---
    // chunk c: A-part (i < 16c) as 16-row runs, e = i*16 + (j - 16c);
    //          then triangle (16c <= i < j < 16c+16).
    for (int g = tid; g < NPAIR; g += NT) {
        int c = (g < 120) ? 0 : (g < 496) ? 1 : (g < 1128) ? 2 : 3;
        int e = g - ((c == 0) ? 0 : (c == 1) ? 120 : (c == 2) ? 496 : 1128);
        int i, j;
        if (e < 256 * c) {
            i = e >> 4;
            j = 16 * c + (e & 15);
        } else {
            int f = e - 256 * c, iloc = 0;
            while (f >= 15 - iloc) { f -= 15 - iloc; ++iloc; }
            i = 16 * c + iloc;
            j = i + 1 + f;
        }
        ir[g]  = (unsigned char)i;
        jr[g]  = (unsigned char)j;
        obr[g] = (unsigned short)(i * (127 - i) / 2 + (j - i - 1));
    }

    EXTRACT(0, a0, a1, a2, a3)
    __syncthreads();

    ISSUE(1, b0, b1, b2, b3)
    __builtin_amdgcn_sched_barrier(0);   // pin load issue above the emit
    EMIT(0, 120)
    EXTRACT(1, b0, b1, b2, b3)
    __syncthreads();

    ISSUE(2, c0, c1, c2, c3)
    __builtin_amdgcn_sched_barrier(0);
    EMIT(120, 376)
    EXTRACT(2, c0, c1, c2, c3)
    __syncthreads();

    ISSUE(3, d0, d1, d2, d3)
    __builtin_amdgcn_sched_barrier(0);
    EMIT(496, 632)
    EXTRACT(3, d0, d1, d2, d3)
    __syncthreads();

    EMIT(1128, 888)

#undef ISSUE
#undef EXTRACT
#undef EMIT
}

extern "C" void kernel_launch(void* const* d_in, const int* in_sizes, int n_in,
                              void* d_out, int out_size, void* d_ws, size_t ws_size,
                              hipStream_t stream) {
    const float* x = (const float*)d_in[0];
    float* out = (float*)d_out;
    ts_sub_pipe<<<dim3(NB), dim3(NT), 0, stream>>>((const fx4*)x, (fx4*)out);
}